// Round 2
// baseline (2000.011 us; speedup 1.0000x reference)
//
#include <hip/hip_runtime.h>

#define DEV __device__ __forceinline__

typedef __attribute__((ext_vector_type(8))) short short8;
typedef __attribute__((ext_vector_type(8))) __bf16 bf16x8;
typedef __attribute__((ext_vector_type(4))) float f32x4;

// ---------- constants for this problem ----------
// N=32, T=1024, D=1152, H=16, DH=72, MLP=4608
#define TD      1024
#define DD      1152
#define HH      16
#define DHH     72
#define MLPD    4608
#define QKVN    3456
#define ADAN    6912
#define MROWS   32768      // 32*1024

DEV unsigned short f32_to_bf16(float f) {
  unsigned int u = __float_as_uint(f);
  u += 0x7fffu + ((u >> 16) & 1u);
  return (unsigned short)(u >> 16);
}

DEV void gl16(const void* g, void* l) {
  __builtin_amdgcn_global_load_lds((__attribute__((address_space(1))) void*)g,
                                   (__attribute__((address_space(3))) void*)l,
                                   16, 0, 0);
}

DEV bf16x8 zero_bf16x8() {
  short8 z = {0, 0, 0, 0, 0, 0, 0, 0};
  return __builtin_bit_cast(bf16x8, z);
}

DEV float gelu_exact(float v) {
  return 0.5f * v * (1.0f + erff(v * 0.70710678118654752f));
}

// ---------------- weight transpose: fp32 W[K][N] -> bf16 Wt[N][K] ----------------
__global__ __launch_bounds__(256) void wtrans_kernel(const float* __restrict__ W,
                                                     unsigned short* __restrict__ Wt,
                                                     int K, int N) {
  __shared__ unsigned short tile[32][33];
  const int nb = blockIdx.x * 32, kb = blockIdx.y * 32;
  const int tx = threadIdx.x, ty = threadIdx.y;  // block (32,8)
  #pragma unroll
  for (int i = ty; i < 32; i += 8)
    tile[i][tx] = f32_to_bf16(W[(size_t)(kb + i) * N + nb + tx]);
  __syncthreads();
  #pragma unroll
  for (int i = ty; i < 32; i += 8)
    Wt[(size_t)(nb + i) * K + kb + tx] = tile[tx][i];
}

// ---------------- ada = silu(c) @ ada_w + ada_b  (fp32) ----------------
__global__ __launch_bounds__(256) void ada_kernel(const float* __restrict__ c,
                                                  const float* __restrict__ ada_w,
                                                  const float* __restrict__ ada_b,
                                                  float* __restrict__ ada_out) {
  __shared__ float sc[DD];
  const int n = blockIdx.y;
  const int col = blockIdx.x * 256 + threadIdx.x;
  for (int i = threadIdx.x; i < DD; i += 256) {
    float v = c[(size_t)n * DD + i];
    sc[i] = v / (1.0f + __expf(-v));
  }
  __syncthreads();
  float acc = ada_b[col];
  #pragma unroll 8
  for (int k = 0; k < DD; ++k)
    acc += sc[k] * ada_w[(size_t)k * ADAN + col];
  ada_out[(size_t)n * ADAN + col] = acc;
}

// ---------------- LayerNorm + modulate -> bf16 ----------------
__global__ __launch_bounds__(256) void ln_mod_kernel(const float* __restrict__ X,
                                                     const float* __restrict__ ada,
                                                     int soff,
                                                     unsigned short* __restrict__ out) {
  const int row = blockIdx.x;       // 0..32767
  const int batch = row >> 10;
  const float* xr = X + (size_t)row * DD;
  const int t = threadIdx.x;

  float4 v0 = reinterpret_cast<const float4*>(xr)[t];
  float4 v1 = make_float4(0.f, 0.f, 0.f, 0.f);
  const bool has2 = (t < 32);
  if (has2) v1 = reinterpret_cast<const float4*>(xr)[256 + t];

  float s  = v0.x + v0.y + v0.z + v0.w + v1.x + v1.y + v1.z + v1.w;
  float sq = v0.x*v0.x + v0.y*v0.y + v0.z*v0.z + v0.w*v0.w
           + v1.x*v1.x + v1.y*v1.y + v1.z*v1.z + v1.w*v1.w;
  #pragma unroll
  for (int m = 1; m < 64; m <<= 1) {
    s  += __shfl_xor(s, m);
    sq += __shfl_xor(sq, m);
  }
  __shared__ float red[8];
  const int wv = t >> 6;
  if ((t & 63) == 0) { red[wv] = s; red[4 + wv] = sq; }
  __syncthreads();
  s  = red[0] + red[1] + red[2] + red[3];
  sq = red[4] + red[5] + red[6] + red[7];
  const float mean = s * (1.0f / 1152.0f);
  const float var  = sq * (1.0f / 1152.0f) - mean * mean;
  const float rstd = rsqrtf(var + 1e-6f);

  const float* shp = ada + (size_t)batch * ADAN + soff;
  const float* scp = shp + DD;
  unsigned short* orow = out + (size_t)row * DD;

  {
    const int col = t * 4;
    ushort4 o4;
    o4.x = f32_to_bf16((v0.x - mean) * rstd * (1.0f + scp[col + 0]) + shp[col + 0]);
    o4.y = f32_to_bf16((v0.y - mean) * rstd * (1.0f + scp[col + 1]) + shp[col + 1]);
    o4.z = f32_to_bf16((v0.z - mean) * rstd * (1.0f + scp[col + 2]) + shp[col + 2]);
    o4.w = f32_to_bf16((v0.w - mean) * rstd * (1.0f + scp[col + 3]) + shp[col + 3]);
    reinterpret_cast<ushort4*>(orow)[t] = o4;
  }
  if (has2) {
    const int col = 1024 + t * 4;
    ushort4 o4;
    o4.x = f32_to_bf16((v1.x - mean) * rstd * (1.0f + scp[col + 0]) + shp[col + 0]);
    o4.y = f32_to_bf16((v1.y - mean) * rstd * (1.0f + scp[col + 1]) + shp[col + 1]);
    o4.z = f32_to_bf16((v1.z - mean) * rstd * (1.0f + scp[col + 2]) + shp[col + 2]);
    o4.w = f32_to_bf16((v1.w - mean) * rstd * (1.0f + scp[col + 3]) + shp[col + 3]);
    reinterpret_cast<ushort4*>(orow)[256 + t] = o4;
  }
}

// ---------------- GEMM: C[M][N] = A[M][K](bf16) * Wt[N][K](bf16)^T + epilogue ----------------
// EPI: 0 = +bias -> bf16 (qkv)
//      1 = resid + gate*( +bias ) -> f32 (proj residual into d_out)
//      2 = gelu(+bias) -> bf16 (fc1)
//      3 = out += gate*( +bias ) -> f32 in-place on d_out (fc2)
template <int EPI>
__global__ __launch_bounds__(256) void gemm128(const unsigned short* __restrict__ A,
                                               const unsigned short* __restrict__ Bt,
                                               const float* __restrict__ bias,
                                               const float* __restrict__ ada, int ada_off,
                                               const float* __restrict__ resid,
                                               unsigned short* __restrict__ out_bf,
                                               float* __restrict__ out_f,
                                               int N, int K) {
  __shared__ unsigned short lds[2][8192];  // [buf][ A 128x32 | B 128x32 ]
  const int tid = threadIdx.x;
  const int bn = blockIdx.x, bm = blockIdx.y;
  const int lane = tid & 63, w = tid >> 6;
  const int wm = w >> 1, wn = w & 1;
  const int l15 = lane & 15, lg = lane >> 4;

  const unsigned short* Abase = A + (size_t)bm * 128 * K;
  const unsigned short* Bbase = Bt + (size_t)bn * 128 * K;
  const int c1 = tid, c2 = tid + 256;
  const size_t a1 = (size_t)(c1 >> 2) * K + (c1 & 3) * 8;
  const size_t a2 = (size_t)(c2 >> 2) * K + (c2 & 3) * 8;

  f32x4 acc[4][4];
  #pragma unroll
  for (int m = 0; m < 4; ++m)
    #pragma unroll
    for (int nn = 0; nn < 4; ++nn)
      acc[m][nn] = (f32x4){0.f, 0.f, 0.f, 0.f};

  const int nkt = K >> 5;

#define STAGE(buf, kt) do {                                              \
    const size_t ko = (size_t)(kt) * 32;                                 \
    gl16(Abase + a1 + ko, &lds[buf][c1 * 8]);                            \
    gl16(Abase + a2 + ko, &lds[buf][c2 * 8]);                            \
    gl16(Bbase + a1 + ko, &lds[buf][4096 + c1 * 8]);                     \
    gl16(Bbase + a2 + ko, &lds[buf][4096 + c2 * 8]);                     \
  } while (0)

  STAGE(0, 0);
  for (int kt = 0; kt < nkt; ++kt) {
    __syncthreads();
    if (kt + 1 < nkt) STAGE((kt + 1) & 1, kt + 1);
    const unsigned short* la = lds[kt & 1];
    const unsigned short* lb = la + 4096;
    bf16x8 af[4], bfv[4];
    #pragma unroll
    for (int m = 0; m < 4; ++m)
      af[m] = *(const bf16x8*)&la[(wm * 64 + m * 16 + l15) * 32 + lg * 8];
    #pragma unroll
    for (int nn = 0; nn < 4; ++nn)
      bfv[nn] = *(const bf16x8*)&lb[(wn * 64 + nn * 16 + l15) * 32 + lg * 8];
    #pragma unroll
    for (int m = 0; m < 4; ++m)
      #pragma unroll
      for (int nn = 0; nn < 4; ++nn)
        acc[m][nn] = __builtin_amdgcn_mfma_f32_16x16x32_bf16(af[m], bfv[nn], acc[m][nn], 0, 0, 0);
  }
#undef STAGE

  const int batch = (bm * 128) >> 10;
  const size_t row0 = (size_t)bm * 128 + wm * 64;
  const int col0 = bn * 128 + wn * 64;
  #pragma unroll
  for (int nn = 0; nn < 4; ++nn) {
    const int colg = col0 + nn * 16 + l15;
    const float bv = bias[colg];
    float g = 0.0f;
    if constexpr (EPI == 1 || EPI == 3) g = ada[(size_t)batch * ADAN + ada_off + colg];
    #pragma unroll
    for (int m = 0; m < 4; ++m) {
      #pragma unroll
      for (int r = 0; r < 4; ++r) {
        const size_t idx = (row0 + m * 16 + lg * 4 + r) * (size_t)N + colg;
        const float v = acc[m][nn][r] + bv;
        if constexpr (EPI == 0)      out_bf[idx] = f32_to_bf16(v);
        else if constexpr (EPI == 2) out_bf[idx] = f32_to_bf16(gelu_exact(v));
        else if constexpr (EPI == 1) out_f[idx] = resid[idx] + g * v;
        else                         out_f[idx] = out_f[idx] + g * v;
      }
    }
  }
}

// ---------------- per-token head attention ----------------
// Reference: attn = softmax_k( sum_d q[n,t,h,d]*scale * k[n,t,kh,d] )  (16x16 per token!)
//            oh[n,t,h,d] = sum_kh attn[h,kh] * v[n,t,kh,d]
//            y flat per batch: index h*73728 + t*72 + d, viewed as [1024][1152]
// One wave per token. qkv row layout: [3][16][72] bf16.
__global__ __launch_bounds__(256) void attn_kernel(const unsigned short* __restrict__ qkv,
                                                   unsigned short* __restrict__ y) {
  const int tid = threadIdx.x, w = tid >> 6, lane = tid & 63;
  const int l15 = lane & 15, lg = lane >> 4;
  const int tok = blockIdx.x * 4 + w;          // 0..32767
  const int n = tok >> 10, t = tok & 1023;

  __shared__ unsigned short Pl[4][16 * 32];    // per-wave P, K-padded to 32
  __shared__ unsigned short Vl[4][16 * 80];    // per-wave V[kh][d] (stride 80)

  // zero P's k>=16 half once (only lower half rewritten below)
  for (int i = lane; i < 16 * 32; i += 64)
    if ((i & 31) >= 16) Pl[w][i] = 0;

  const size_t rowb = (size_t)tok * QKVN;
  const float scale = 0.11785113019775793f;    // 72^-0.5

  // Q fragment: A row = q-head = l15, k = lg*8+j (dh), guarded at 72
  bf16x8 aq[3];
  #pragma unroll
  for (int kk = 0; kk < 3; ++kk) {
    const int d0 = kk * 32 + lg * 8;
    aq[kk] = (d0 < DHH) ? *(const bf16x8*)&qkv[rowb + l15 * DHH + d0] : zero_bf16x8();
  }

  // stage V rows (16 x 72) into per-wave LDS
  for (int c = lane; c < 144; c += 64) {
    const int r = c / 9, cc = (c % 9) * 8;
    *(short8*)&Vl[w][r * 80 + cc] = *(const short8*)&qkv[rowb + 2 * DD + r * DHH + cc];
  }

  // S = Q K^T : B col = k-head = l15, k = dh
  f32x4 s = (f32x4){0.f, 0.f, 0.f, 0.f};
  #pragma unroll
  for (int kk = 0; kk < 3; ++kk) {
    const int d0 = kk * 32 + lg * 8;
    bf16x8 bk = (d0 < DHH) ? *(const bf16x8*)&qkv[rowb + DD + l15 * DHH + d0] : zero_bf16x8();
    s = __builtin_amdgcn_mfma_f32_16x16x32_bf16(aq[kk], bk, s, 0, 0, 0);
  }

  // softmax over k-head (= across the 16 lanes of each lg-group)
  // rows: q-head = lg*4 + r
  float p[4], mx[4], ssum[4];
  #pragma unroll
  for (int r = 0; r < 4; ++r) { p[r] = s[r] * scale; mx[r] = p[r]; }
  #pragma unroll
  for (int mk = 1; mk <= 8; mk <<= 1)
    #pragma unroll
    for (int r = 0; r < 4; ++r) mx[r] = fmaxf(mx[r], __shfl_xor(mx[r], mk));
  #pragma unroll
  for (int r = 0; r < 4; ++r) { p[r] = __expf(p[r] - mx[r]); ssum[r] = p[r]; }
  #pragma unroll
  for (int mk = 1; mk <= 8; mk <<= 1)
    #pragma unroll
    for (int r = 0; r < 4; ++r) ssum[r] += __shfl_xor(ssum[r], mk);

  // normalized P -> LDS (row = q-head, col = k-head)
  #pragma unroll
  for (int r = 0; r < 4; ++r)
    Pl[w][(lg * 4 + r) * 32 + l15] = f32_to_bf16(p[r] / ssum[r]);

  // PV: A = P (row = q-head = l15, k = k-head = lg*8+j; k>=16 half is zero)
  bf16x8 pa = *(const bf16x8*)&Pl[w][l15 * 32 + lg * 8];
  const int kb = (lg & 1) * 8;  // keep B reads in-bounds; lg>=2 garbage * A=0
  f32x4 o[5];
  #pragma unroll
  for (int df = 0; df < 5; ++df) {
    short8 bvv;
    #pragma unroll
    for (int j = 0; j < 8; ++j)
      bvv[j] = (short)Vl[w][(kb + j) * 80 + df * 16 + l15];
    o[df] = __builtin_amdgcn_mfma_f32_16x16x32_bf16(
        pa, __builtin_bit_cast(bf16x8, bvv), (f32x4){0.f, 0.f, 0.f, 0.f}, 0, 0, 0);
  }

  // scatter: y[n][ h*73728 + t*72 + d ], h = lg*4+r, d = df*16+l15
  unsigned short* yb = y + (size_t)n * (TD * DD);
  #pragma unroll
  for (int df = 0; df < 5; ++df) {
    const int d = df * 16 + l15;
    if (d < DHH) {
      #pragma unroll
      for (int r = 0; r < 4; ++r) {
        const int h = lg * 4 + r;
        yb[h * 73728 + t * DHH + d] = f32_to_bf16(o[df][r]);
      }
    }
  }
}

// ---------------- host launch ----------------
extern "C" void kernel_launch(void* const* d_in, const int* in_sizes, int n_in,
                              void* d_out, int out_size, void* d_ws, size_t ws_size,
                              hipStream_t stream) {
  (void)in_sizes; (void)n_in; (void)out_size; (void)ws_size;
  const float* x      = (const float*)d_in[0];
  const float* c      = (const float*)d_in[1];
  const float* qkv_w  = (const float*)d_in[2];
  const float* qkv_b  = (const float*)d_in[3];
  const float* proj_w = (const float*)d_in[4];
  const float* proj_b = (const float*)d_in[5];
  const float* fc1_w  = (const float*)d_in[6];
  const float* fc1_b  = (const float*)d_in[7];
  const float* fc2_w  = (const float*)d_in[8];
  const float* fc2_b  = (const float*)d_in[9];
  const float* ada_w  = (const float*)d_in[10];
  const float* ada_b  = (const float*)d_in[11];
  float* out = (float*)d_out;

  char* ws = (char*)d_ws;
  // region reused: [qkv bf16 (226.5MB) | attn-y bf16 (75.5MB)] then as h bf16 (302MB)
  unsigned short* hbuf    = (unsigned short*)ws;
  unsigned short* qkvbuf  = hbuf;
  unsigned short* attnbuf = hbuf + (size_t)MROWS * QKVN;
  size_t off = 301989888ull;
  unsigned short* xm    = (unsigned short*)(ws + off); off += 75497472ull;
  unsigned short* wtq   = (unsigned short*)(ws + off); off += 7962624ull;
  unsigned short* wtp   = (unsigned short*)(ws + off); off += 2654208ull;
  unsigned short* wtf1  = (unsigned short*)(ws + off); off += 10616832ull;
  unsigned short* wtf2  = (unsigned short*)(ws + off); off += 10616832ull;
  float*          adab  = (float*)(ws + off); off += 884736ull;

  const dim3 tb(32, 8);
  hipLaunchKernelGGL(wtrans_kernel, dim3(QKVN / 32, DD / 32), tb, 0, stream, qkv_w, wtq, DD, QKVN);
  hipLaunchKernelGGL(wtrans_kernel, dim3(DD / 32, DD / 32),   tb, 0, stream, proj_w, wtp, DD, DD);
  hipLaunchKernelGGL(wtrans_kernel, dim3(MLPD / 32, DD / 32), tb, 0, stream, fc1_w, wtf1, DD, MLPD);
  hipLaunchKernelGGL(wtrans_kernel, dim3(DD / 32, MLPD / 32), tb, 0, stream, fc2_w, wtf2, MLPD, DD);

  hipLaunchKernelGGL(ada_kernel, dim3(ADAN / 256, 32), dim3(256), 0, stream, c, ada_w, ada_b, adab);

  hipLaunchKernelGGL(ln_mod_kernel, dim3(MROWS), dim3(256), 0, stream, x, adab, 0, xm);

  hipLaunchKernelGGL((gemm128<0>), dim3(QKVN / 128, MROWS / 128), dim3(256), 0, stream,
                     xm, wtq, qkv_b, nullptr, 0, nullptr, qkvbuf, nullptr, QKVN, DD);

  hipLaunchKernelGGL(attn_kernel, dim3(MROWS / 4), dim3(256), 0, stream, qkvbuf, attnbuf);

  hipLaunchKernelGGL((gemm128<1>), dim3(DD / 128, MROWS / 128), dim3(256), 0, stream,
                     attnbuf, wtp, proj_b, adab, 2304, x, nullptr, out, DD, DD);

  hipLaunchKernelGGL(ln_mod_kernel, dim3(MROWS), dim3(256), 0, stream, out, adab, 3456, xm);

  hipLaunchKernelGGL((gemm128<2>), dim3(MLPD / 128, MROWS / 128), dim3(256), 0, stream,
                     xm, wtf1, fc1_b, nullptr, 0, nullptr, hbuf, nullptr, MLPD, DD);

  hipLaunchKernelGGL((gemm128<3>), dim3(DD / 128, MROWS / 128), dim3(256), 0, stream,
                     hbuf, wtf2, fc2_b, adab, 5760, nullptr, nullptr, out, DD, MLPD);
}